// Round 2
// baseline (1204.186 us; speedup 1.0000x reference)
//
#include <hip/hip_runtime.h>

#define B_ 2
#define N_ 2048
#define E_ 1024
#define H_ 16
#define D_ 64
#define T_ (B_*N_)   // 4096 tokens

// ---------------------------------------------------------------------------
// Tiled fp32 GEMM: C[M,1024] = X[M,1024] @ W[1024,1024] + bias
// 64x64 tile per block, 256 threads, 4x4 micro-tile per thread.
// PERMUTE: store as (b, h, n, d) for attention consumption.
// ---------------------------------------------------------------------------
template<bool PERMUTE>
__global__ __launch_bounds__(256)
void gemm_k(const float* __restrict__ X, const float* __restrict__ W,
            const float* __restrict__ bias, float* __restrict__ out)
{
    __shared__ __align__(16) float As[16][68];  // As[k][m], stride 68 keeps 16B align, <=2-way conflicts
    __shared__ __align__(16) float Bs[16][68];  // Bs[k][n]
    const int tid  = threadIdx.x;
    const int row0 = blockIdx.x * 64;
    const int col0 = blockIdx.y * 64;
    const int tx = tid & 15, ty = tid >> 4;
    const int am = tid >> 2, ak = (tid & 3) << 2;   // A: 4 rows of k per thread
    const int bk = tid >> 4, bn = (tid & 15) << 2;  // B: float4 along n

    float acc[4][4] = {};

    for (int k0 = 0; k0 < E_; k0 += 16) {
        const float4 a = *(const float4*)&X[(size_t)(row0 + am)*E_ + k0 + ak];
        const float4 b = *(const float4*)&W[(size_t)(k0 + bk)*E_ + col0 + bn];
        __syncthreads();   // previous iteration's reads done
        As[ak+0][am] = a.x; As[ak+1][am] = a.y; As[ak+2][am] = a.z; As[ak+3][am] = a.w;
        *(float4*)&Bs[bk][bn] = b;
        __syncthreads();
        #pragma unroll
        for (int k = 0; k < 16; ++k) {
            float aa[4], bb[4];
            {
                const float4 t = *(const float4*)&As[k][ty<<2];
                aa[0]=t.x; aa[1]=t.y; aa[2]=t.z; aa[3]=t.w;
            }
            {
                const float4 t = *(const float4*)&Bs[k][tx<<2];
                bb[0]=t.x; bb[1]=t.y; bb[2]=t.z; bb[3]=t.w;
            }
            #pragma unroll
            for (int i = 0; i < 4; ++i)
                #pragma unroll
                for (int j = 0; j < 4; ++j)
                    acc[i][j] += aa[i]*bb[j];
        }
    }

    const int r_ = row0 + (ty<<2);
    const int c_ = col0 + (tx<<2);
    const float4 b4 = *(const float4*)&bias[c_];
    #pragma unroll
    for (int i = 0; i < 4; ++i) {
        float4 o;
        o.x = acc[i][0] + b4.x; o.y = acc[i][1] + b4.y;
        o.z = acc[i][2] + b4.z; o.w = acc[i][3] + b4.w;
        const int r = r_ + i;
        if (PERMUTE) {
            // r = b*2048 + n ; c_ = h*64 + d (d..d+3 within one head since col0,tx*4 stay inside 64)
            const int b  = r >> 11;
            const int n  = r & (N_-1);
            const int h  = c_ >> 6;
            const int d  = c_ & 63;
            *(float4*)&out[(((size_t)(b*H_ + h))*N_ + n)*D_ + d] = o;
        } else {
            *(float4*)&out[(size_t)r*E_ + c_] = o;
        }
    }
}

// ---------------------------------------------------------------------------
// Flash-style fp32 attention. One block = 64 Q rows of one (b,h).
// Q,K,V are (b,h,n,d). K staged transposed (KT[d][c]) so all inner ds_reads
// are float4 with <=2-way bank conflicts; P reuses the KT buffer.
// Out written as (b, n, e). Includes the reference's post-softmax /32.
// ---------------------------------------------------------------------------
__global__ __launch_bounds__(256)
void attn_k(const float* __restrict__ Q, const float* __restrict__ K,
            const float* __restrict__ V, float* __restrict__ Out)
{
    __shared__ __align__(16) float Qs[64][68];   // Qs[r][d]
    __shared__ __align__(16) float KT[64][68];   // KT[d][c]; reused as Ps[r][c]
    __shared__ __align__(16) float Vs[64][68];   // Vs[c][d]

    const int tid = threadIdx.x;
    const int bh  = blockIdx.y;            // b*H + h
    const int q0  = blockIdx.x * 64;
    const float* Qb = Q + (size_t)bh*N_*D_;
    const float* Kb = K + (size_t)bh*N_*D_;
    const float* Vb = V + (size_t)bh*N_*D_;
    const int tx = tid & 15, ty = tid >> 4;

    // load Q tile (rows q0..q0+63)
    {
        const int r  = tid >> 4;           // 0..15
        const int dq = (tid & 15) << 2;    // 0..60
        #pragma unroll
        for (int l = 0; l < 4; ++l) {
            const float4 t = *(const float4*)&Qb[(size_t)(q0 + r + l*16)*D_ + dq];
            *(float4*)&Qs[r + l*16][dq] = t;
        }
    }

    float m_run[4], l_run[4], o[4][4];
    #pragma unroll
    for (int i = 0; i < 4; ++i) {
        m_run[i] = -1e30f; l_run[i] = 0.f;
        #pragma unroll
        for (int j = 0; j < 4; ++j) o[i][j] = 0.f;
    }

    for (int kv0 = 0; kv0 < N_; kv0 += 64) {
        // stage K (transposed) and V
        {
            const int r  = tid >> 4;
            const int dq = (tid & 15) << 2;
            #pragma unroll
            for (int l = 0; l < 4; ++l) {
                const float4 kt = *(const float4*)&Kb[(size_t)(kv0 + r + l*16)*D_ + dq];
                KT[dq+0][r+l*16] = kt.x; KT[dq+1][r+l*16] = kt.y;
                KT[dq+2][r+l*16] = kt.z; KT[dq+3][r+l*16] = kt.w;
                const float4 vt = *(const float4*)&Vb[(size_t)(kv0 + r + l*16)*D_ + dq];
                *(float4*)&Vs[r+l*16][dq] = vt;
            }
        }
        __syncthreads();

        // S = Q K^T  (rows ty*4+i, cols tx*4+j)
        float s[4][4] = {};
        #pragma unroll
        for (int d0 = 0; d0 < D_; d0 += 4) {
            float qa[4][4], ka[4][4];
            #pragma unroll
            for (int i = 0; i < 4; ++i) {
                const float4 t = *(const float4*)&Qs[(ty<<2)+i][d0];
                qa[i][0]=t.x; qa[i][1]=t.y; qa[i][2]=t.z; qa[i][3]=t.w;
            }
            #pragma unroll
            for (int m = 0; m < 4; ++m) {
                const float4 t = *(const float4*)&KT[d0+m][tx<<2];
                ka[m][0]=t.x; ka[m][1]=t.y; ka[m][2]=t.z; ka[m][3]=t.w;
            }
            #pragma unroll
            for (int i = 0; i < 4; ++i)
                #pragma unroll
                for (int j = 0; j < 4; ++j)
                    #pragma unroll
                    for (int m = 0; m < 4; ++m)
                        s[i][j] += qa[i][m]*ka[m][j];
        }

        // online softmax update (row groups = 16 lanes sharing ty)
        #pragma unroll
        for (int i = 0; i < 4; ++i) {
            float mt = fmaxf(fmaxf(s[i][0], s[i][1]), fmaxf(s[i][2], s[i][3]));
            #pragma unroll
            for (int w = 1; w < 16; w <<= 1)
                mt = fmaxf(mt, __shfl_xor(mt, w, 64));
            const float mnew  = fmaxf(m_run[i], mt);
            const float scale = __expf(m_run[i] - mnew);
            float psum = 0.f;
            #pragma unroll
            for (int j = 0; j < 4; ++j) {
                s[i][j] = __expf(s[i][j] - mnew);
                psum += s[i][j];
            }
            #pragma unroll
            for (int w = 1; w < 16; w <<= 1)
                psum += __shfl_xor(psum, w, 64);
            l_run[i] = l_run[i]*scale + psum;
            m_run[i] = mnew;
            #pragma unroll
            for (int j = 0; j < 4; ++j) o[i][j] *= scale;
        }

        __syncthreads();   // everyone done reading KT before overwriting with P
        #pragma unroll
        for (int i = 0; i < 4; ++i)
            *(float4*)&KT[(ty<<2)+i][tx<<2] = make_float4(s[i][0], s[i][1], s[i][2], s[i][3]);
        __syncthreads();

        // O += P @ V  (o rows ty*4+i, cols d = tx*4+j)
        #pragma unroll
        for (int k0 = 0; k0 < 64; k0 += 4) {
            float pa[4][4], va[4][4];
            #pragma unroll
            for (int i = 0; i < 4; ++i) {
                const float4 t = *(const float4*)&KT[(ty<<2)+i][k0];
                pa[i][0]=t.x; pa[i][1]=t.y; pa[i][2]=t.z; pa[i][3]=t.w;
            }
            #pragma unroll
            for (int m = 0; m < 4; ++m) {
                const float4 t = *(const float4*)&Vs[k0+m][tx<<2];
                va[m][0]=t.x; va[m][1]=t.y; va[m][2]=t.z; va[m][3]=t.w;
            }
            #pragma unroll
            for (int i = 0; i < 4; ++i)
                #pragma unroll
                for (int j = 0; j < 4; ++j)
                    #pragma unroll
                    for (int m = 0; m < 4; ++m)
                        o[i][j] += pa[i][m]*va[m][j];
        }
        __syncthreads();   // before next tile overwrites KT/Vs
    }

    // epilogue: normalize, apply the reference's post-softmax /sqrt(E)=/32,
    // store as (b, n, e)
    const int bb = bh >> 4;
    const int hh = bh & 15;
    #pragma unroll
    for (int i = 0; i < 4; ++i) {
        const int n   = q0 + (ty<<2) + i;
        const float inv = 1.0f / (l_run[i] * 32.0f);
        const float4 o4 = make_float4(o[i][0]*inv, o[i][1]*inv, o[i][2]*inv, o[i][3]*inv);
        *(float4*)&Out[((size_t)bb*N_ + n)*E_ + hh*D_ + (tx<<2)] = o4;
    }
}

// ---------------------------------------------------------------------------
extern "C" void kernel_launch(void* const* d_in, const int* in_sizes, int n_in,
                              void* d_out, int out_size, void* d_ws, size_t ws_size,
                              hipStream_t stream)
{
    const float* x  = (const float*)d_in[0];
    const float* Wq = (const float*)d_in[1];
    const float* bq = (const float*)d_in[2];
    const float* Wk = (const float*)d_in[3];
    const float* bk = (const float*)d_in[4];
    const float* Wv = (const float*)d_in[5];
    const float* bv = (const float*)d_in[6];
    const float* Wo = (const float*)d_in[7];
    const float* bo = (const float*)d_in[8];
    float* out = (float*)d_out;

    const size_t per = (size_t)B_*H_*N_*D_;   // 4,194,304 floats
    float* q  = (float*)d_ws;
    float* k  = q + per;
    float* v  = k + per;
    float* ao = v + per;                      // (b, n, e)

    dim3 gg(T_/64, E_/64);      // 64 x 16
    gemm_k<true ><<<gg, 256, 0, stream>>>(x,  Wq, bq, q);
    gemm_k<true ><<<gg, 256, 0, stream>>>(x,  Wk, bk, k);
    gemm_k<true ><<<gg, 256, 0, stream>>>(x,  Wv, bv, v);

    dim3 ga(N_/64, B_*H_);      // 32 x 32
    attn_k<<<ga, 256, 0, stream>>>(q, k, v, ao);

    gemm_k<false><<<gg, 256, 0, stream>>>(ao, Wo, bo, out);
}

// Round 3
// 597.241 us; speedup vs baseline: 2.0163x; 2.0163x over previous
//
#include <hip/hip_runtime.h>
#include <hip/hip_bf16.h>

#define B_ 2
#define N_ 2048
#define E_ 1024
#define H_ 16
#define D_ 64
#define T_ (B_*N_)   // 4096 tokens

using s16x8 = __attribute__((ext_vector_type(8))) short;
using f32x4 = __attribute__((ext_vector_type(4))) float;

static __device__ __forceinline__ short f2bf(float f) {
    __hip_bfloat16 h = __float2bfloat16(f);
    union { __hip_bfloat16 h; short s; } u; u.h = h; return u.s;
}
static __device__ __forceinline__ float bf2f(short s) {
    union { short s; __hip_bfloat16 h; } u; u.s = s;
    return __bfloat162float(u.h);
}

// ---------------------------------------------------------------------------
// split x (fp32) -> xh, xl (bf16 hi/lo)
// ---------------------------------------------------------------------------
__global__ __launch_bounds__(256)
void split_x_k(const float* __restrict__ x, short* __restrict__ xh, short* __restrict__ xl)
{
    const int total = (T_*E_)/4;
    for (int i = blockIdx.x*256 + threadIdx.x; i < total; i += gridDim.x*256) {
        const float4 v = ((const float4*)x)[i];
        short h0 = f2bf(v.x), h1 = f2bf(v.y), h2 = f2bf(v.z), h3 = f2bf(v.w);
        short l0 = f2bf(v.x - bf2f(h0)), l1 = f2bf(v.y - bf2f(h1));
        short l2 = f2bf(v.z - bf2f(h2)), l3 = f2bf(v.w - bf2f(h3));
        short4 hs; hs.x=h0; hs.y=h1; hs.z=h2; hs.w=h3;
        short4 ls; ls.x=l0; ls.y=l1; ls.z=l2; ls.w=l3;
        ((short4*)xh)[i] = hs;
        ((short4*)xl)[i] = ls;
    }
}

// ---------------------------------------------------------------------------
// split + transpose W (fp32 [k][n]) -> WhT (, WlT) bf16 [n][k]
// ---------------------------------------------------------------------------
template<int SPLIT>
__global__ __launch_bounds__(256)
void splitwT_k(const float* __restrict__ W, short* __restrict__ WhT, short* __restrict__ WlT)
{
    __shared__ float Ts[64][65];
    const int t = threadIdx.x;
    const int kb = blockIdx.x*64, nb = blockIdx.y*64;
    const int r = t>>4, c4 = (t&15)*4;
    #pragma unroll
    for (int l = 0; l < 4; ++l) {
        const float4 v = *(const float4*)&W[(size_t)(kb + r + l*16)*E_ + nb + c4];
        Ts[c4+0][r+l*16] = v.x; Ts[c4+1][r+l*16] = v.y;
        Ts[c4+2][r+l*16] = v.z; Ts[c4+3][r+l*16] = v.w;
    }
    __syncthreads();
    #pragma unroll
    for (int l = 0; l < 4; ++l) {
        const int np = r + l*16;
        float v0 = Ts[np][c4+0], v1 = Ts[np][c4+1], v2 = Ts[np][c4+2], v3 = Ts[np][c4+3];
        short4 hs; hs.x=f2bf(v0); hs.y=f2bf(v1); hs.z=f2bf(v2); hs.w=f2bf(v3);
        *(short4*)&WhT[(size_t)(nb + np)*E_ + kb + c4] = hs;
        if (SPLIT) {
            short4 ls;
            ls.x = f2bf(v0 - bf2f(hs.x)); ls.y = f2bf(v1 - bf2f(hs.y));
            ls.z = f2bf(v2 - bf2f(hs.z)); ls.w = f2bf(v3 - bf2f(hs.w));
            *(short4*)&WlT[(size_t)(nb + np)*E_ + kb + c4] = ls;
        }
    }
}

// ---------------------------------------------------------------------------
// MFMA GEMM: C[4096,1024] = sum of NPROD products A_p @ B_p^T, + bias.
// A: [4096][1024] bf16 row-major; B given transposed [n][k] bf16.
// No LDS: fragments loaded directly from global (16B/lane, full-line use).
// EPI 0: fp32 out [t][e]. EPI 1: split hi/lo bf16 to [b,h,n,d].
// EPI 2: bf16 transposed to [b,h,d,n].
// Grid: 256 blocks 1D, bm=i>>3 (32), bn=i&7 (8) -> each XCD owns one n-panel.
// ---------------------------------------------------------------------------
template<int NPROD, int EPI>
__global__ __launch_bounds__(256)
void gemm_mfma_k(const short* __restrict__ Ah, const short* __restrict__ Al,
                 const short* __restrict__ Bh, const short* __restrict__ Bl,
                 const float* __restrict__ bias, void* __restrict__ out0,
                 void* __restrict__ out1)
{
    const int lane = threadIdx.x & 63, wid = threadIdx.x >> 6;
    const int lr = lane & 15, lg = lane >> 4;
    const int bm = blockIdx.x >> 3, bn = blockIdx.x & 7;
    const int gm0 = bm*128 + (wid>>1)*64;
    const int gn0 = bn*128 + (wid&1)*64;

    f32x4 acc[4][4];
    #pragma unroll
    for (int i = 0; i < 4; ++i)
        #pragma unroll
        for (int j = 0; j < 4; ++j)
            acc[i][j] = (f32x4){0.f,0.f,0.f,0.f};

    for (int ks = 0; ks < 32; ++ks) {
        const int kk = ks*32 + lg*8;
        s16x8 a0[4], a1[4], b0[4], b1[4];
        #pragma unroll
        for (int mi = 0; mi < 4; ++mi) {
            a0[mi] = *(const s16x8*)(Ah + (size_t)(gm0 + mi*16 + lr)*E_ + kk);
            if (NPROD == 3) a1[mi] = *(const s16x8*)(Al + (size_t)(gm0 + mi*16 + lr)*E_ + kk);
        }
        #pragma unroll
        for (int ni = 0; ni < 4; ++ni) {
            b0[ni] = *(const s16x8*)(Bh + (size_t)(gn0 + ni*16 + lr)*E_ + kk);
            if (NPROD == 3) b1[ni] = *(const s16x8*)(Bl + (size_t)(gn0 + ni*16 + lr)*E_ + kk);
        }
        #pragma unroll
        for (int mi = 0; mi < 4; ++mi)
            #pragma unroll
            for (int ni = 0; ni < 4; ++ni) {
                acc[mi][ni] = __builtin_amdgcn_mfma_f32_16x16x32_bf16(a0[mi], b0[ni], acc[mi][ni], 0, 0, 0);
                if (NPROD == 3) {
                    acc[mi][ni] = __builtin_amdgcn_mfma_f32_16x16x32_bf16(a0[mi], b1[ni], acc[mi][ni], 0, 0, 0);
                    acc[mi][ni] = __builtin_amdgcn_mfma_f32_16x16x32_bf16(a1[mi], b0[ni], acc[mi][ni], 0, 0, 0);
                }
            }
    }

    #pragma unroll
    for (int mi = 0; mi < 4; ++mi)
        #pragma unroll
        for (int ni = 0; ni < 4; ++ni) {
            const int gn = gn0 + ni*16 + lr;
            const float bv = bias[gn];
            if (EPI == 0) {
                float* out = (float*)out0;
                #pragma unroll
                for (int r = 0; r < 4; ++r) {
                    const int row = gm0 + mi*16 + lg*4 + r;
                    out[(size_t)row*E_ + gn] = acc[mi][ni][r] + bv;
                }
            } else if (EPI == 1) {
                short* oh = (short*)out0; short* ol = (short*)out1;
                const int h = gn >> 6, d = gn & 63;
                #pragma unroll
                for (int r = 0; r < 4; ++r) {
                    const int row = gm0 + mi*16 + lg*4 + r;
                    const int b = row >> 11, n = row & (N_-1);
                    const size_t idx = (((size_t)(b*H_ + h))*N_ + n)*D_ + d;
                    const float v = acc[mi][ni][r] + bv;
                    const short hi = f2bf(v);
                    oh[idx] = hi;
                    ol[idx] = f2bf(v - bf2f(hi));
                }
            } else {
                short* ov = (short*)out0;
                const int h = gn >> 6, d = gn & 63;
                const int row0 = gm0 + mi*16 + lg*4;
                const int b = row0 >> 11, n0 = row0 & (N_-1);
                short4 s4;
                s4.x = f2bf(acc[mi][ni][0] + bv);
                s4.y = f2bf(acc[mi][ni][1] + bv);
                s4.z = f2bf(acc[mi][ni][2] + bv);
                s4.w = f2bf(acc[mi][ni][3] + bv);
                *(short4*)&ov[(((size_t)(b*H_ + h))*D_ + d)*N_ + n0] = s4;
            }
        }
}

// ---------------------------------------------------------------------------
// MFMA flash attention. 4 waves x 32 q-rows = 128 q-rows per block.
// QK^T in bf16x2 (3 products); softmax fp32; PV in bf16.
// K frags read directly from global [b,h,n,d]; V from pre-transposed [b,h,d,n].
// P redistributed per-wave via LDS (no block barriers at all).
// Applies the reference's post-softmax /sqrt(E) = /32.
// ---------------------------------------------------------------------------
__global__ __launch_bounds__(256)
void attn_mfma_k(const short* __restrict__ qh, const short* __restrict__ ql,
                 const short* __restrict__ kh, const short* __restrict__ kl,
                 const short* __restrict__ vT, short* __restrict__ aO)
{
    __shared__ __align__(16) short P[128][72];

    const int i = blockIdx.x;
    const int xcd = i & 7, j = i >> 3;
    const int bh = xcd*4 + (j >> 4);       // 0..31, chunked per XCD for L2 reuse
    const int q0 = (j & 15) * 128;

    const int lane = threadIdx.x & 63, wid = threadIdx.x >> 6;
    const int lr = lane & 15, lg = lane >> 4;
    const int wq = wid * 32;

    const short* qhb = qh + (size_t)bh*N_*D_;
    const short* qlb = ql + (size_t)bh*N_*D_;
    const short* khb = kh + (size_t)bh*N_*D_;
    const short* klb = kl + (size_t)bh*N_*D_;
    const short* vb  = vT + (size_t)bh*D_*N_;

    // Q fragments resident in registers
    s16x8 q0f[2][2], q1f[2][2];
    #pragma unroll
    for (int mi = 0; mi < 2; ++mi)
        #pragma unroll
        for (int kc = 0; kc < 2; ++kc) {
            const size_t off = (size_t)(q0 + wq + mi*16 + lr)*D_ + kc*32 + lg*8;
            q0f[mi][kc] = *(const s16x8*)(qhb + off);
            q1f[mi][kc] = *(const s16x8*)(qlb + off);
        }

    f32x4 o[2][4];
    float m_run[2][4], l_run[2][4];
    #pragma unroll
    for (int mi = 0; mi < 2; ++mi) {
        #pragma unroll
        for (int ni = 0; ni < 4; ++ni) o[mi][ni] = (f32x4){0.f,0.f,0.f,0.f};
        #pragma unroll
        for (int r = 0; r < 4; ++r) { m_run[mi][r] = -3.0e38f; l_run[mi][r] = 0.f; }
    }

    for (int kv0 = 0; kv0 < N_; kv0 += 64) {
        // ---- S = Q K^T (bf16x2, 3 products) ----
        f32x4 s[2][4];
        #pragma unroll
        for (int mi = 0; mi < 2; ++mi)
            #pragma unroll
            for (int ni = 0; ni < 4; ++ni) s[mi][ni] = (f32x4){0.f,0.f,0.f,0.f};

        #pragma unroll
        for (int kc = 0; kc < 2; ++kc)
            #pragma unroll
            for (int ni = 0; ni < 4; ++ni) {
                const size_t off = (size_t)(kv0 + ni*16 + lr)*D_ + kc*32 + lg*8;
                const s16x8 kh8 = *(const s16x8*)(khb + off);
                const s16x8 kl8 = *(const s16x8*)(klb + off);
                #pragma unroll
                for (int mi = 0; mi < 2; ++mi) {
                    s[mi][ni] = __builtin_amdgcn_mfma_f32_16x16x32_bf16(q0f[mi][kc], kh8, s[mi][ni], 0, 0, 0);
                    s[mi][ni] = __builtin_amdgcn_mfma_f32_16x16x32_bf16(q0f[mi][kc], kl8, s[mi][ni], 0, 0, 0);
                    s[mi][ni] = __builtin_amdgcn_mfma_f32_16x16x32_bf16(q1f[mi][kc], kh8, s[mi][ni], 0, 0, 0);
                }
            }

        // ---- online softmax (row stats across 16 lanes x 4 ni) ----
        #pragma unroll
        for (int mi = 0; mi < 2; ++mi)
            #pragma unroll
            for (int r = 0; r < 4; ++r) {
                float mt = fmaxf(fmaxf(s[mi][0][r], s[mi][1][r]),
                                 fmaxf(s[mi][2][r], s[mi][3][r]));
                mt = fmaxf(mt, __shfl_xor(mt, 1));
                mt = fmaxf(mt, __shfl_xor(mt, 2));
                mt = fmaxf(mt, __shfl_xor(mt, 4));
                mt = fmaxf(mt, __shfl_xor(mt, 8));
                const float mnew = fmaxf(m_run[mi][r], mt);
                const float sc   = __expf(m_run[mi][r] - mnew);
                float ps = 0.f;
                #pragma unroll
                for (int ni = 0; ni < 4; ++ni) {
                    const float p = __expf(s[mi][ni][r] - mnew);
                    s[mi][ni][r] = p;
                    ps += p;
                }
                ps += __shfl_xor(ps, 1);
                ps += __shfl_xor(ps, 2);
                ps += __shfl_xor(ps, 4);
                ps += __shfl_xor(ps, 8);
                l_run[mi][r] = l_run[mi][r]*sc + ps;
                m_run[mi][r] = mnew;
                #pragma unroll
                for (int ni = 0; ni < 4; ++ni) o[mi][ni][r] *= sc;
            }

        // ---- P -> LDS (own wave's rows only; no block sync needed) ----
        #pragma unroll
        for (int mi = 0; mi < 2; ++mi)
            #pragma unroll
            for (int ni = 0; ni < 4; ++ni)
                #pragma unroll
                for (int r = 0; r < 4; ++r)
                    P[wq + mi*16 + lg*4 + r][ni*16 + lr] = f2bf(s[mi][ni][r]);

        // ---- O += P @ V ----
        #pragma unroll
        for (int kc = 0; kc < 2; ++kc) {
            s16x8 p8[2];
            #pragma unroll
            for (int mi = 0; mi < 2; ++mi)
                p8[mi] = *(const s16x8*)&P[wq + mi*16 + lr][kc*32 + lg*8];
            #pragma unroll
            for (int ni = 0; ni < 4; ++ni) {
                const s16x8 v8 = *(const s16x8*)(vb + (size_t)(ni*16 + lr)*N_ + kv0 + kc*32 + lg*8);
                #pragma unroll
                for (int mi = 0; mi < 2; ++mi)
                    o[mi][ni] = __builtin_amdgcn_mfma_f32_16x16x32_bf16(p8[mi], v8, o[mi][ni], 0, 0, 0);
            }
        }
    }

    // ---- epilogue: /l, /32, store bf16 [t][e] for output GEMM ----
    const int b = bh >> 4, h = bh & 15;
    #pragma unroll
    for (int mi = 0; mi < 2; ++mi)
        #pragma unroll
        for (int r = 0; r < 4; ++r) {
            const float inv = 1.0f / (l_run[mi][r] * 32.0f);
            const int n = q0 + wq + mi*16 + lg*4 + r;
            #pragma unroll
            for (int ni = 0; ni < 4; ++ni) {
                const int e = h*64 + ni*16 + lr;
                aO[(size_t)(b*N_ + n)*E_ + e] = f2bf(o[mi][ni][r] * inv);
            }
        }
}

// ---------------------------------------------------------------------------
extern "C" void kernel_launch(void* const* d_in, const int* in_sizes, int n_in,
                              void* d_out, int out_size, void* d_ws, size_t ws_size,
                              hipStream_t stream)
{
    const float* x  = (const float*)d_in[0];
    const float* Wq = (const float*)d_in[1];
    const float* bq = (const float*)d_in[2];
    const float* Wk = (const float*)d_in[3];
    const float* bk = (const float*)d_in[4];
    const float* Wv = (const float*)d_in[5];
    const float* bv = (const float*)d_in[6];
    const float* Wo = (const float*)d_in[7];
    const float* bo = (const float*)d_in[8];
    float* out = (float*)d_out;

    const size_t MB = 1024*1024ULL;
    char* ws = (char*)d_ws;
    short* xh  = (short*)(ws + 0*MB);    // 8 MB
    short* xl  = (short*)(ws + 8*MB);    // 8 MB
    short* WhT = (short*)(ws + 16*MB);   // 2 MB
    short* WlT = (short*)(ws + 18*MB);   // 2 MB
    short* vT  = (short*)(ws + 20*MB);   // 8 MB  [b,h,d,n]
    short* qh  = (short*)(ws + 28*MB);   // 8 MB  [b,h,n,d]
    short* ql  = (short*)(ws + 36*MB);
    short* kh  = (short*)(ws + 44*MB);
    short* kl  = (short*)(ws + 52*MB);
    short* aO  = (short*)(ws + 0*MB);    // aliases xh (dead after K-proj)

    dim3 gw(16, 16);

    split_x_k<<<1024, 256, 0, stream>>>(x, xh, xl);

    // V projection (plain bf16), output pre-transposed [b,h,d,n]
    splitwT_k<0><<<gw, 256, 0, stream>>>(Wv, WhT, nullptr);
    gemm_mfma_k<1,2><<<256, 256, 0, stream>>>(xh, nullptr, WhT, nullptr, bv, vT, nullptr);

    // Q projection (bf16x2, 3 products), split outputs
    splitwT_k<1><<<gw, 256, 0, stream>>>(Wq, WhT, WlT);
    gemm_mfma_k<3,1><<<256, 256, 0, stream>>>(xh, xl, WhT, WlT, bq, qh, ql);

    // K projection
    splitwT_k<1><<<gw, 256, 0, stream>>>(Wk, WhT, WlT);
    gemm_mfma_k<3,1><<<256, 256, 0, stream>>>(xh, xl, WhT, WlT, bk, kh, kl);

    // attention
    attn_mfma_k<<<512, 256, 0, stream>>>(qh, ql, kh, kl, vT, aO);

    // output projection (plain bf16 -> fp32 out)
    splitwT_k<0><<<gw, 256, 0, stream>>>(Wo, WhT, nullptr);
    gemm_mfma_k<1,0><<<256, 256, 0, stream>>>(aO, nullptr, WhT, nullptr, bo, out, nullptr);
}